// Round 10
// baseline (4311.594 us; speedup 1.0000x reference)
//
#include <hip/hip_runtime.h>
#include <hip/hip_cooperative_groups.h>

namespace cg = cooperative_groups;

#define T_  512
#define B_  64
#define F_  256
#define E_  512
#define AGENT __HIP_MEMORY_SCOPE_AGENT
#define WGRP  __HIP_MEMORY_SCOPE_WORKGROUP

typedef __bf16 bf16x8 __attribute__((ext_vector_type(8)));
typedef float  f32x4  __attribute__((ext_vector_type(4)));

// ---- ws layout (bytes). Write-once rings; DATA IS THE SIGNAL:
// rings pre-poisoned with bf16 NaN (0x7FC0). h = sigmoid*tanh in (-1,1)
// never rounds to NaN, so consumers poll the data itself with agent-scope
// loads until every bf16 half is non-NaN.
// Layout: enc ring[t][g=e>>3][b][8 dims] bf16, dec ring[t][g=f>>2][b][4] bf16
#define OFF_HF   0ull                    // [513][64][64][8] bf16 = 33,619,968
#define OFF_HB   33619968ull             // same
#define OFF_HD   67239936ull             // [513][64][64][4] bf16 = 16,809,984
#define OFF_XP   84049920ull             // [4F][B] f32 = 262,144
#define OFF_SL   84312064ull             // slotsX[128], slotsF[64], slotsB[64]

// ---- LDS arena (bytes); weights live here for the whole kernel ----
#define L_WHH_H 0        // ushort[32][520]
#define L_WHH_L 33280
#define L_WIH_H 66560    // ushort[32][264]
#define L_WIH_L 83456
#define L_DWH_H 100352   // ushort[16][264]
#define L_DWH_L 108800
#define L_PRE   117248   // float[32][68]
#define L_XBUF  125952   // float[DEPTH=4][4 grp][2 tile][64 lane][4] = 32 KiB
#define L_FLG   158720   // u32 wcnt[4], rcnt[4]
#define L_TOTAL 158976
#define LDK_H 520        // whh lds row stride (ushorts)
#define LDK_X 264        // wih/dwhh stride
#define LDP   68         // pre row stride (floats)
#define XDEPTH 4

#define NANP 0x7fc07fc07fc07fc0ull
#define K1_  0x0001000100010001ull
#define K8_  0x8000800080008000ull

__device__ __forceinline__ float sigmoidf_(float x) {
    return __builtin_amdgcn_rcpf(1.0f + __expf(-x));
}
__device__ __forceinline__ float tanhf_(float x) {
    return 1.0f - 2.0f * __builtin_amdgcn_rcpf(1.0f + __expf(2.0f * x));
}
__device__ __forceinline__ unsigned short f2bf(float f) {   // RNE
    unsigned u = __float_as_uint(f);
    u += 0x7fffu + ((u >> 16) & 1u);
    return (unsigned short)(u >> 16);
}
__device__ __forceinline__ float bfbits2f(unsigned us) {
    return __uint_as_float(us << 16);
}
__device__ __forceinline__ void astore_u32(unsigned* p, unsigned v) {
    __hip_atomic_store(p, v, __ATOMIC_RELAXED, AGENT);
}
__device__ __forceinline__ unsigned aload_u32(const unsigned* p) {
    return __hip_atomic_load(p, __ATOMIC_RELAXED, AGENT);
}
__device__ __forceinline__ void astore_u64(unsigned long long* p, unsigned long long v) {
    __hip_atomic_store(p, v, __ATOMIC_RELAXED, AGENT);
}
__device__ __forceinline__ unsigned long long aload_u64(const unsigned long long* p) {
    return __hip_atomic_load(p, __ATOMIC_RELAXED, AGENT);
}
__device__ __forceinline__ void astore_f(float* p, float v) {
    __hip_atomic_store(p, v, __ATOMIC_RELAXED, AGENT);
}
__device__ __forceinline__ unsigned lds_ld(const unsigned* p) {
    return __hip_atomic_load(p, __ATOMIC_RELAXED, WGRP);
}
__device__ __forceinline__ void lds_st(unsigned* p, unsigned v) {
    __hip_atomic_store(p, v, __ATOMIC_RELAXED, WGRP);
}
// any 16-bit half of v equal to bf16 NaN 0x7fc0?
__device__ __forceinline__ unsigned long long nanmask(unsigned long long v) {
    unsigned long long x = v ^ NANP;
    return (x - K1_) & ~x & K8_;
}

__global__ __launch_bounds__(512, 2)
void autoenc_kernel(const float* __restrict__ seq,
                    const float* __restrict__ WihF, const float* __restrict__ WhhF, const float* __restrict__ bF,
                    const float* __restrict__ WihB, const float* __restrict__ WhhB, const float* __restrict__ bB,
                    const float* __restrict__ dWih, const float* __restrict__ dWhh, const float* __restrict__ db,
                    float* __restrict__ out, char* __restrict__ ws)
{
    cg::grid_group grid = cg::this_grid();
    const int tid = threadIdx.x;
    const int bid = blockIdx.x;

    unsigned short* hfR = (unsigned short*)(ws + OFF_HF);
    unsigned short* hbR = (unsigned short*)(ws + OFF_HB);
    unsigned short* hdR = (unsigned short*)(ws + OFF_HD);
    float* xp0T = (float*)(ws + OFF_XP);
    unsigned* slotsX = (unsigned*)(ws + OFF_SL);   // [128]
    unsigned* slotsF = slotsX + 128;               // [64]
    unsigned* slotsB = slotsX + 192;               // [64]

    __shared__ __align__(16) char arena[L_TOTAL];
    unsigned short* whhH = (unsigned short*)(arena + L_WHH_H);
    unsigned short* whhL = (unsigned short*)(arena + L_WHH_L);
    unsigned short* wihH = (unsigned short*)(arena + L_WIH_H);
    unsigned short* wihL = (unsigned short*)(arena + L_WIH_L);
    unsigned short* dwhH = (unsigned short*)(arena + L_DWH_H);
    unsigned short* dwhL = (unsigned short*)(arena + L_DWH_L);
    float* pre = (float*)(arena + L_PRE);
    float* xpool = (float*)(arena + L_XBUF);
    unsigned* wcnt = (unsigned*)(arena + L_FLG);   // [4], writer: wave 4+nt
    unsigned* rcnt = wcnt + 4;                     // [4], writer: wave nt

    const int dir = bid >> 6;          // 0 fwd (blocks 0..63), 1 bwd (64..127)
    const int blk = bid & 63;
    const int e0  = blk * 8;           // encoder block owns h dims [e0, e0+8)
    const float* Wih  = dir ? WihB : WihF;
    const float* Whh  = dir ? WhhB : WhhF;
    const float* bias = dir ? bB   : bF;
    unsigned short* ring = dir ? hbR : hfR;

    // ---- init: zero slab 0, NaN-poison slabs 1..512, zero slots ----
    {
        unsigned long long* hf64 = (unsigned long long*)hfR;
        unsigned long long* hb64 = (unsigned long long*)hbR;
        unsigned long long* hd64 = (unsigned long long*)hdR;
        const int gstep = 128 * 512;
        for (int i = bid * 512 + tid; i < 8192; i += gstep) { astore_u64(hf64 + i, 0ull); astore_u64(hb64 + i, 0ull); }
        for (int i = bid * 512 + tid; i < 4096; i += gstep) astore_u64(hd64 + i, 0ull);
        for (int i = 8192 + bid * 512 + tid; i < 4202496; i += gstep) { astore_u64(hf64 + i, NANP); astore_u64(hb64 + i, NANP); }
        for (int i = 4096 + bid * 512 + tid; i < 2101248; i += gstep) astore_u64(hd64 + i, NANP);
        if (bid == 0 && tid < 256) astore_u32(slotsX + tid, 0u);
    }
    if (tid < 8) wcnt[tid] = 0u;   // zero wcnt[4] + rcnt[4]

    // ---- one-time weight conversion fp32 -> bf16 hi/lo in LDS ----
    for (int idx = tid; idx < 32 * 512; idx += 512) {        // Whh 32 rows x 512
        int r = idx >> 9, k = idx & 511;
        int grow = (r >> 3) * E_ + e0 + (r & 7);
        float w0 = Whh[(size_t)grow * E_ + k];
        __bf16 h16 = (__bf16)w0;
        __bf16 l16 = (__bf16)(w0 - (float)h16);
        whhH[r * LDK_H + k] = __builtin_bit_cast(unsigned short, h16);
        whhL[r * LDK_H + k] = __builtin_bit_cast(unsigned short, l16);
    }
    for (int idx = tid; idx < 32 * 256; idx += 512) {        // Wih 32 rows x 256
        int r = idx >> 8, k = idx & 255;
        int grow = (r >> 3) * E_ + e0 + (r & 7);
        float w0 = Wih[(size_t)grow * F_ + k];
        __bf16 h16 = (__bf16)w0;
        __bf16 l16 = (__bf16)(w0 - (float)h16);
        wihH[r * LDK_X + k] = __builtin_bit_cast(unsigned short, h16);
        wihL[r * LDK_X + k] = __builtin_bit_cast(unsigned short, l16);
    }
    if (bid < 64) {                                          // dec Whh 16 rows x 256
        const int fb0 = bid * 4;
        for (int idx = tid; idx < 16 * 256; idx += 512) {
            int r = idx >> 8, k = idx & 255;
            int grow = (r >> 2) * F_ + fb0 + (r & 3);
            float w0 = dWhh[(size_t)grow * F_ + k];
            __bf16 h16 = (__bf16)w0;
            __bf16 l16 = (__bf16)(w0 - (float)h16);
            dwhH[r * LDK_X + k] = __builtin_bit_cast(unsigned short, h16);
            dwhL[r * LDK_X + k] = __builtin_bit_cast(unsigned short, l16);
        }
    }
    __syncthreads();
    grid.sync();   // poison + ring[0] + slots + flags visible before any poll

    const int w    = tid >> 6;        // wave 0..7
    const int lane = tid & 63;
    const int col  = lane & 15;
    const int quad = lane >> 4;

    // ================= encoder =================
    // Waves 0..3 (consumers): wave nt runs the recurrence for batches
    // [16nt,16nt+16): poll h(t), h-MFMA (acc seeded with xacc from LDS),
    // private pre slice, own epilogue + ring store. No barriers.
    // Waves 4..7 (x-producers): wave 4+nt computes the h-independent
    // x-projection for group nt, runs ahead, publishes into a DEPTH=4 LDS
    // ring (single-writer wcnt / single-reader rcnt per group).
    {
        if (w >= 4) {
            // ---------- x-producer ----------
            const int nt = w - 4;
            const int bcol = nt * 16 + col;
            const unsigned short* aX0h = wihH + col * LDK_X + quad * 8;
            const unsigned short* aX0l = wihL + col * LDK_X + quad * 8;
            const unsigned short* aX1h = wihH + (16 + col) * LDK_X + quad * 8;
            const unsigned short* aX1l = wihL + (16 + col) * LDK_X + quad * 8;

            for (int t = 0; t < T_; ++t) {
                // wait for slab space (consumer released t-XDEPTH)
                if (t >= XDEPTH) {
                    while (lds_ld(rcnt + nt) < (unsigned)(t - XDEPTH + 1))
                        __builtin_amdgcn_s_sleep(2);
                    asm volatile("" ::: "memory");
                }
                const int t_eff = dir ? (T_ - 1 - t) : t;
                f32x4 xc0 = {0.f, 0.f, 0.f, 0.f};
                f32x4 xd0 = xc0, xc1 = xc0, xd1 = xc0;
                const float* xrow = seq + (size_t)t_eff * B_ * F_ + bcol * F_ + quad * 8;
                #pragma unroll
                for (int kt = 0; kt < 8; ++kt) {
                    float4 v0 = *(const float4*)(xrow + kt * 32);
                    float4 v1 = *(const float4*)(xrow + kt * 32 + 4);
                    float vv[8] = {v0.x, v0.y, v0.z, v0.w, v1.x, v1.y, v1.z, v1.w};
                    bf16x8 xh, xl;
                    #pragma unroll
                    for (int j2 = 0; j2 < 8; ++j2) {
                        __bf16 hvv = (__bf16)vv[j2];
                        xh[j2] = hvv;
                        xl[j2] = (__bf16)(vv[j2] - (float)hvv);
                    }
                    bf16x8 a0h = *(const bf16x8*)(aX0h + kt * 32);
                    bf16x8 a0l = *(const bf16x8*)(aX0l + kt * 32);
                    bf16x8 a1h = *(const bf16x8*)(aX1h + kt * 32);
                    bf16x8 a1l = *(const bf16x8*)(aX1l + kt * 32);
                    xc0 = __builtin_amdgcn_mfma_f32_16x16x32_bf16(a0h, xh, xc0, 0, 0, 0);
                    xd0 = __builtin_amdgcn_mfma_f32_16x16x32_bf16(a0l, xh, xd0, 0, 0, 0);
                    xc0 = __builtin_amdgcn_mfma_f32_16x16x32_bf16(a0h, xl, xc0, 0, 0, 0);
                    xc1 = __builtin_amdgcn_mfma_f32_16x16x32_bf16(a1h, xh, xc1, 0, 0, 0);
                    xd1 = __builtin_amdgcn_mfma_f32_16x16x32_bf16(a1l, xh, xd1, 0, 0, 0);
                    xc1 = __builtin_amdgcn_mfma_f32_16x16x32_bf16(a1h, xl, xc1, 0, 0, 0);
                }
                float* xb = xpool + (size_t)(((t & (XDEPTH - 1)) * 4 + nt) * 2) * 256 + lane * 4;
                *(f32x4*)xb         = xc0 + xd0;
                *(f32x4*)(xb + 256) = xc1 + xd1;
                asm volatile("s_waitcnt lgkmcnt(0)" ::: "memory");
                __builtin_amdgcn_sched_barrier(0);
                if (lane == 0) lds_st(wcnt + nt, (unsigned)(t + 1));
            }
        } else {
            // ---------- recurrence consumer ----------
            const int nt = w;
            const int bcol = nt * 16 + col;
            const unsigned short* aH0h = whhH + col * LDK_H + quad * 8;
            const unsigned short* aH0l = whhL + col * LDK_H + quad * 8;
            const unsigned short* aH1h = whhH + (16 + col) * LDK_H + quad * 8;
            const unsigned short* aH1l = whhL + (16 + col) * LDK_H + quad * 8;

            const unsigned long long* encHp =
                (const unsigned long long*)ring + (size_t)quad * 128 + (size_t)bcol * 2;

            // epilogue: lane owns dims {ej0, ej0+1} of batch eb (within group nt)
            const int colb = lane >> 2;
            const int ej0  = (lane & 3) * 2;
            const int eb   = nt * 16 + colb;
            const float bGi0 = bias[0 * E_ + e0 + ej0], bGi1 = bias[0 * E_ + e0 + ej0 + 1];
            const float bGf0 = bias[1 * E_ + e0 + ej0], bGf1 = bias[1 * E_ + e0 + ej0 + 1];
            const float bGg0 = bias[2 * E_ + e0 + ej0], bGg1 = bias[2 * E_ + e0 + ej0 + 1];
            const float bGo0 = bias[3 * E_ + e0 + ej0], bGo1 = bias[3 * E_ + e0 + ej0 + 1];
            float c0 = 0.0f, c1 = 0.0f;
            unsigned* ringO = (unsigned*)ring;

            for (int t = 0; t < T_; ++t) {
                // ---- poll h_t (plain full reload; R6-proven) ----
                unsigned long long hv[32];
                {
                    const unsigned long long* hpT = encHp + (size_t)t * 8192;
                    for (;;) {
                        #pragma unroll
                        for (int kt = 0; kt < 16; ++kt) {
                            hv[2 * kt]     = aload_u64(hpT + kt * 512);
                            hv[2 * kt + 1] = aload_u64(hpT + kt * 512 + 1);
                        }
                        unsigned long long m = 0;
                        #pragma unroll
                        for (int i = 0; i < 32; ++i) m |= nanmask(hv[i]);
                        if (!__any(m != 0ull)) break;
                        __builtin_amdgcn_s_sleep(1);
                    }
                    asm volatile("" ::: "memory");
                }

                // ---- xacc from producer (almost always ready) ----
                while (lds_ld(wcnt + nt) < (unsigned)(t + 1))
                    __builtin_amdgcn_s_sleep(1);
                asm volatile("" ::: "memory");
                const float* xb = xpool + (size_t)(((t & (XDEPTH - 1)) * 4 + nt) * 2) * 256 + lane * 4;
                f32x4 xacc0 = *(const f32x4*)xb;
                f32x4 xacc1 = *(const f32x4*)(xb + 256);

                // ---- h-part MFMA: acc seeded with xacc ----
                f32x4 p00 = xacc0;
                f32x4 p01 = {0.f, 0.f, 0.f, 0.f};
                f32x4 q00 = p01, q01 = p01;
                f32x4 p10 = xacc1;
                f32x4 p11 = p01, q10 = p01, q11 = p01;
                #pragma unroll
                for (int kt = 0; kt < 8; ++kt) {
                    ulonglong2 qv; qv.x = hv[2 * kt]; qv.y = hv[2 * kt + 1];
                    bf16x8 hb = __builtin_bit_cast(bf16x8, qv);
                    p00 = __builtin_amdgcn_mfma_f32_16x16x32_bf16(*(const bf16x8*)(aH0h + kt * 32), hb, p00, 0, 0, 0);
                    q00 = __builtin_amdgcn_mfma_f32_16x16x32_bf16(*(const bf16x8*)(aH0l + kt * 32), hb, q00, 0, 0, 0);
                    p10 = __builtin_amdgcn_mfma_f32_16x16x32_bf16(*(const bf16x8*)(aH1h + kt * 32), hb, p10, 0, 0, 0);
                    q10 = __builtin_amdgcn_mfma_f32_16x16x32_bf16(*(const bf16x8*)(aH1l + kt * 32), hb, q10, 0, 0, 0);
                }
                #pragma unroll
                for (int kt = 8; kt < 16; ++kt) {
                    ulonglong2 qv; qv.x = hv[2 * kt]; qv.y = hv[2 * kt + 1];
                    bf16x8 hb = __builtin_bit_cast(bf16x8, qv);
                    p01 = __builtin_amdgcn_mfma_f32_16x16x32_bf16(*(const bf16x8*)(aH0h + kt * 32), hb, p01, 0, 0, 0);
                    q01 = __builtin_amdgcn_mfma_f32_16x16x32_bf16(*(const bf16x8*)(aH0l + kt * 32), hb, q01, 0, 0, 0);
                    p11 = __builtin_amdgcn_mfma_f32_16x16x32_bf16(*(const bf16x8*)(aH1h + kt * 32), hb, p11, 0, 0, 0);
                    q11 = __builtin_amdgcn_mfma_f32_16x16x32_bf16(*(const bf16x8*)(aH1l + kt * 32), hb, q11, 0, 0, 0);
                }
                f32x4 s0 = (p00 + p01) + (q00 + q01);
                f32x4 s1 = (p10 + p11) + (q10 + q11);

                // release the xacc slab (registers hold the data now)
                if (lane == 0) lds_st(rcnt + nt, (unsigned)(t + 1));

                // ---- wave-private dump (column slice nt*16..+16); no barrier ----
                #pragma unroll
                for (int rg = 0; rg < 4; ++rg) {
                    pre[(quad * 4 + rg) * LDP + nt * 16 + col]      = s0[rg];
                    pre[(16 + quad * 4 + rg) * LDP + nt * 16 + col] = s1[rg];
                }
                asm volatile("s_waitcnt lgkmcnt(0)" ::: "memory");
                __builtin_amdgcn_sched_barrier(0);

                // ---- epilogue: 2 h-values per lane ----
                {
                    float gI0 = pre[(0 * 8 + ej0) * LDP + nt * 16 + colb] + bGi0;
                    float gF0 = pre[(1 * 8 + ej0) * LDP + nt * 16 + colb] + bGf0;
                    float gG0 = pre[(2 * 8 + ej0) * LDP + nt * 16 + colb] + bGg0;
                    float gO0 = pre[(3 * 8 + ej0) * LDP + nt * 16 + colb] + bGo0;
                    float gI1 = pre[(0 * 8 + ej0 + 1) * LDP + nt * 16 + colb] + bGi1;
                    float gF1 = pre[(1 * 8 + ej0 + 1) * LDP + nt * 16 + colb] + bGf1;
                    float gG1 = pre[(2 * 8 + ej0 + 1) * LDP + nt * 16 + colb] + bGg1;
                    float gO1 = pre[(3 * 8 + ej0 + 1) * LDP + nt * 16 + colb] + bGo1;
                    c0 = sigmoidf_(gF0) * c0 + sigmoidf_(gI0) * tanhf_(gG0);
                    c1 = sigmoidf_(gF1) * c1 + sigmoidf_(gI1) * tanhf_(gG1);
                    float h0 = sigmoidf_(gO0) * tanhf_(c0);
                    float h1 = sigmoidf_(gO1) * tanhf_(c1);
                    unsigned pk = (unsigned)f2bf(h0) | ((unsigned)f2bf(h1) << 16);
                    astore_u32(ringO + (size_t)(t + 1) * 16384 + blk * 256 + eb * 4 + (lane & 3), pk);
                }
            }
        }
        // one-time end-of-encoder signal (for xp0 join); all 8 waves arrive
        __syncthreads();   // drains working waves' ring stores
        if (tid == 0) astore_u32((dir ? slotsB : slotsF) + blk, 1u);
        // join both directions
        if (tid < 64) {
            bool ok = (aload_u32(slotsF + tid) != 0u) && (aload_u32(slotsB + tid) != 0u);
            while (!__all(ok)) {
                __builtin_amdgcn_s_sleep(4);
                ok = (aload_u32(slotsF + tid) != 0u) && (aload_u32(slotsB + tid) != 0u);
            }
            asm volatile("" ::: "memory");
        }
        __syncthreads();
    }

    // ================= xp0 = [h_f | h_b] @ dec_Wih^T + dec_b =================
    {
        const int r8 = tid >> 6, xb = tid & 63;
        const int r = bid * 8 + r8;                       // 0..1023
        const float* wr = dWih + (size_t)r * (2 * E_);    // wave-uniform row
        float accv = db[r];
        const unsigned long long* hfq = (const unsigned long long*)hfR + (size_t)T_ * 8192 + xb * 2;
        const unsigned long long* hbq = (const unsigned long long*)hbR + (size_t)T_ * 8192 + xb * 2;
        for (int g = 0; g < 64; ++g) {
            unsigned long long v0 = hfq[g * 128], v1 = hfq[g * 128 + 1];
            accv = fmaf(wr[g * 8 + 0], bfbits2f((unsigned)(v0 & 0xffff)), accv);
            accv = fmaf(wr[g * 8 + 1], bfbits2f((unsigned)((v0 >> 16) & 0xffff)), accv);
            accv = fmaf(wr[g * 8 + 2], bfbits2f((unsigned)((v0 >> 32) & 0xffff)), accv);
            accv = fmaf(wr[g * 8 + 3], bfbits2f((unsigned)((v0 >> 48) & 0xffff)), accv);
            accv = fmaf(wr[g * 8 + 4], bfbits2f((unsigned)(v1 & 0xffff)), accv);
            accv = fmaf(wr[g * 8 + 5], bfbits2f((unsigned)((v1 >> 16) & 0xffff)), accv);
            accv = fmaf(wr[g * 8 + 6], bfbits2f((unsigned)((v1 >> 32) & 0xffff)), accv);
            accv = fmaf(wr[g * 8 + 7], bfbits2f((unsigned)((v1 >> 48) & 0xffff)), accv);
        }
        for (int g = 0; g < 64; ++g) {
            unsigned long long v0 = hbq[g * 128], v1 = hbq[g * 128 + 1];
            accv = fmaf(wr[E_ + g * 8 + 0], bfbits2f((unsigned)(v0 & 0xffff)), accv);
            accv = fmaf(wr[E_ + g * 8 + 1], bfbits2f((unsigned)((v0 >> 16) & 0xffff)), accv);
            accv = fmaf(wr[E_ + g * 8 + 2], bfbits2f((unsigned)((v0 >> 32) & 0xffff)), accv);
            accv = fmaf(wr[E_ + g * 8 + 3], bfbits2f((unsigned)((v0 >> 48) & 0xffff)), accv);
            accv = fmaf(wr[E_ + g * 8 + 4], bfbits2f((unsigned)(v1 & 0xffff)), accv);
            accv = fmaf(wr[E_ + g * 8 + 5], bfbits2f((unsigned)((v1 >> 16) & 0xffff)), accv);
            accv = fmaf(wr[E_ + g * 8 + 6], bfbits2f((unsigned)((v1 >> 32) & 0xffff)), accv);
            accv = fmaf(wr[E_ + g * 8 + 7], bfbits2f((unsigned)((v1 >> 48) & 0xffff)), accv);
        }
        astore_f(&xp0T[r * B_ + xb], accv);
        __syncthreads();         // drain all waves' xp0 stores
        if (tid == 0) astore_u32(slotsX + bid, 1u);
        if (bid >= 64) return;
        if (tid < 64) {
            bool ok = (aload_u32(slotsX + tid) != 0u) && (aload_u32(slotsX + 64 + tid) != 0u);
            while (!__all(ok)) {
                __builtin_amdgcn_s_sleep(4);
                ok = (aload_u32(slotsX + tid) != 0u) && (aload_u32(slotsX + 64 + tid) != 0u);
            }
            asm volatile("" ::: "memory");
        }
        __syncthreads();
    }

    // ================= decoder: 64 blocks x 4 f-dims (MFMA) =================
    // R6 kh-split: each wave polls HALF the producers (parallel straggler
    // waits on different SIMDs), joined by barrier B; barrier C protects pre
    // from next-iteration overwrites (REQUIRED: a kh wave's poll only covers
    // the opposite half's producer blocks — learned in R8).
    {
        const int fb0 = bid * 4;
        const int ntD = w & 3, kh = w >> 2;      // N-tile, K-half per wave
        const int bcolD = ntD * 16 + col;
        const unsigned short* aDh = dwhH + col * LDK_X + kh * 128 + quad * 8;
        const unsigned short* aDl = dwhL + col * LDK_X + kh * 128 + quad * 8;

        // consumer frag base: u64 units. g0 = kh*32 + kt*8 + quad*2;
        const unsigned long long* decHp =
            (const unsigned long long*)hdR + (size_t)(kh * 32 + quad * 2) * 64 + bcolD;
        unsigned* hdO = (unsigned*)hdR;

        const int ej = tid & 3, eb = tid >> 2;   // epilogue (j,b) for tid<256
        float xg0 = 0, xg1 = 0, xg2 = 0, xg3 = 0;
        if (tid < 256) {
            xg0 = xp0T[(0 * F_ + fb0 + ej) * B_ + eb];
            xg1 = xp0T[(1 * F_ + fb0 + ej) * B_ + eb];
            xg2 = xp0T[(2 * F_ + fb0 + ej) * B_ + eb];
            xg3 = xp0T[(3 * F_ + fb0 + ej) * B_ + eb];
        }
        float creg = 0.0f;

        for (int t = 0; t < T_; ++t) {
            // ---- poll-load h_t frags (plain full reload) ----
            unsigned long long hv[8];
            {
                const unsigned long long* hpT = decHp + (size_t)t * 4096;
                for (;;) {
                    #pragma unroll
                    for (int kt = 0; kt < 4; ++kt) {
                        hv[2 * kt]     = aload_u64(hpT + kt * 512);
                        hv[2 * kt + 1] = aload_u64(hpT + kt * 512 + 64);
                    }
                    unsigned long long m = 0;
                    #pragma unroll
                    for (int i = 0; i < 8; ++i) m |= nanmask(hv[i]);
                    if (!__any(m != 0ull)) break;
                    __builtin_amdgcn_s_sleep(1);
                }
                asm volatile("" ::: "memory");
            }

            f32x4 accA = {0.f, 0.f, 0.f, 0.f};
            f32x4 accB = accA;
            #pragma unroll
            for (int kt = 0; kt < 4; ++kt) {
                ulonglong2 q; q.x = hv[2 * kt]; q.y = hv[2 * kt + 1];
                bf16x8 hb = __builtin_bit_cast(bf16x8, q);
                bf16x8 ah = *(const bf16x8*)(aDh + kt * 32);
                bf16x8 al = *(const bf16x8*)(aDl + kt * 32);
                accA = __builtin_amdgcn_mfma_f32_16x16x32_bf16(ah, hb, accA, 0, 0, 0);
                accB = __builtin_amdgcn_mfma_f32_16x16x32_bf16(al, hb, accB, 0, 0, 0);
            }
            {
                f32x4 s = accA + accB;
                #pragma unroll
                for (int rg = 0; rg < 4; ++rg)
                    pre[kh * (16 * LDP) + (quad * 4 + rg) * LDP + ntD * 16 + col] = s[rg];
            }
            asm volatile("s_waitcnt lgkmcnt(0)" ::: "memory");
            __builtin_amdgcn_sched_barrier(0);
            __builtin_amdgcn_s_barrier();        // barrier B: pre complete

            if (tid < 256) {
                float gI = pre[(0 * 4 + ej) * LDP + eb] + pre[16 * LDP + (0 * 4 + ej) * LDP + eb] + xg0;
                float gF = pre[(1 * 4 + ej) * LDP + eb] + pre[16 * LDP + (1 * 4 + ej) * LDP + eb] + xg1;
                float gG = pre[(2 * 4 + ej) * LDP + eb] + pre[16 * LDP + (2 * 4 + ej) * LDP + eb] + xg2;
                float gO = pre[(3 * 4 + ej) * LDP + eb] + pre[16 * LDP + (3 * 4 + ej) * LDP + eb] + xg3;
                creg = sigmoidf_(gF) * creg + sigmoidf_(gI) * tanhf_(gG);
                float h = sigmoidf_(gO) * tanhf_(creg);
                unsigned hb16 = (unsigned)f2bf(h);
                unsigned hN = __shfl_down(hb16, 1);
                if ((ej & 1) == 0) {
                    astore_u32(hdO + (size_t)(t + 1) * 8192 + bid * 128 + eb * 2 + (ej >> 1),
                               hb16 | (hN << 16));
                }
                out[(size_t)t * B_ * F_ + (size_t)eb * F_ + fb0 + ej] = h;
            }
            asm volatile("" ::: "memory");
            __builtin_amdgcn_s_barrier();        // barrier C: protect pre reuse
            asm volatile("" ::: "memory");
        }
    }
}

extern "C" void kernel_launch(void* const* d_in, const int* in_sizes, int n_in,
                              void* d_out, int out_size, void* d_ws, size_t ws_size,
                              hipStream_t stream) {
    const float* seq  = (const float*)d_in[0];
    const float* WihF = (const float*)d_in[1];
    const float* WhhF = (const float*)d_in[2];
    const float* bF   = (const float*)d_in[3];
    const float* WihB = (const float*)d_in[4];
    const float* WhhB = (const float*)d_in[5];
    const float* bB   = (const float*)d_in[6];
    const float* dWih = (const float*)d_in[7];
    const float* dWhh = (const float*)d_in[8];
    const float* db   = (const float*)d_in[9];
    float* out = (float*)d_out;
    char* ws   = (char*)d_ws;

    void* args[] = { &seq, &WihF, &WhhF, &bF, &WihB, &WhhB, &bB,
                     &dWih, &dWhh, &db, &out, &ws };
    hipLaunchCooperativeKernel((void*)autoenc_kernel, dim3(128), dim3(512),
                               args, 0, stream);
}

// Round 11
// 4200.872 us; speedup vs baseline: 1.0264x; 1.0264x over previous
//
#include <hip/hip_runtime.h>
#include <hip/hip_cooperative_groups.h>

namespace cg = cooperative_groups;

#define T_  512
#define B_  64
#define F_  256
#define E_  512
#define AGENT __HIP_MEMORY_SCOPE_AGENT

typedef __bf16 bf16x8 __attribute__((ext_vector_type(8)));
typedef float  f32x4  __attribute__((ext_vector_type(4)));

// ---- ws layout (bytes). Write-once rings; DATA IS THE SIGNAL:
// rings pre-poisoned with bf16 NaN (0x7FC0). h = sigmoid*tanh in (-1,1)
// never rounds to NaN, so consumers poll the data itself with agent-scope
// loads until every bf16 half is non-NaN.
// Layout: enc ring[t][g=e>>3][b][8 dims] bf16, dec ring[t][g=f>>2][b][4] bf16
#define OFF_HF   0ull                    // [513][64][64][8] bf16 = 33,619,968
#define OFF_HB   33619968ull             // same
#define OFF_HD   67239936ull             // [513][64][64][4] bf16 = 16,809,984
#define OFF_XP   84049920ull             // [4F][B] f32 = 262,144
#define OFF_SL   84312064ull             // slotsX[128], slotsF[64], slotsB[64]

// ---- LDS arena (bytes); weights live here for the whole kernel ----
#define L_WHH_H 0        // ushort[32][520]
#define L_WHH_L 33280
#define L_WIH_H 66560    // ushort[32][264]
#define L_WIH_L 83456
#define L_DWH_H 100352   // ushort[16][264]
#define L_DWH_L 108800
#define L_PRE   117248   // float[32][68]
#define L_TOTAL 125952
#define LDK_H 520        // whh lds row stride (ushorts)
#define LDK_X 264        // wih/dwhh stride
#define LDP   68         // pre row stride (floats)

#define NANP 0x7fc07fc07fc07fc0ull
#define K1_  0x0001000100010001ull
#define K8_  0x8000800080008000ull

__device__ __forceinline__ float sigmoidf_(float x) {
    return __builtin_amdgcn_rcpf(1.0f + __expf(-x));
}
__device__ __forceinline__ float tanhf_(float x) {
    return 1.0f - 2.0f * __builtin_amdgcn_rcpf(1.0f + __expf(2.0f * x));
}
__device__ __forceinline__ unsigned short f2bf(float f) {   // RNE
    unsigned u = __float_as_uint(f);
    u += 0x7fffu + ((u >> 16) & 1u);
    return (unsigned short)(u >> 16);
}
__device__ __forceinline__ float bfbits2f(unsigned us) {
    return __uint_as_float(us << 16);
}
__device__ __forceinline__ void astore_u32(unsigned* p, unsigned v) {
    __hip_atomic_store(p, v, __ATOMIC_RELAXED, AGENT);
}
__device__ __forceinline__ unsigned aload_u32(const unsigned* p) {
    return __hip_atomic_load(p, __ATOMIC_RELAXED, AGENT);
}
__device__ __forceinline__ void astore_u64(unsigned long long* p, unsigned long long v) {
    __hip_atomic_store(p, v, __ATOMIC_RELAXED, AGENT);
}
__device__ __forceinline__ unsigned long long aload_u64(const unsigned long long* p) {
    return __hip_atomic_load(p, __ATOMIC_RELAXED, AGENT);
}
__device__ __forceinline__ void astore_f(float* p, float v) {
    __hip_atomic_store(p, v, __ATOMIC_RELAXED, AGENT);
}
// any 16-bit half of v equal to bf16 NaN 0x7fc0?
__device__ __forceinline__ unsigned long long nanmask(unsigned long long v) {
    unsigned long long x = v ^ NANP;
    return (x - K1_) & ~x & K8_;
}

__global__ __launch_bounds__(512, 2)
void autoenc_kernel(const float* __restrict__ seq,
                    const float* __restrict__ WihF, const float* __restrict__ WhhF, const float* __restrict__ bF,
                    const float* __restrict__ WihB, const float* __restrict__ WhhB, const float* __restrict__ bB,
                    const float* __restrict__ dWih, const float* __restrict__ dWhh, const float* __restrict__ db,
                    float* __restrict__ out, char* __restrict__ ws)
{
    cg::grid_group grid = cg::this_grid();
    const int tid = threadIdx.x;
    const int bid = blockIdx.x;

    unsigned short* hfR = (unsigned short*)(ws + OFF_HF);
    unsigned short* hbR = (unsigned short*)(ws + OFF_HB);
    unsigned short* hdR = (unsigned short*)(ws + OFF_HD);
    float* xp0T = (float*)(ws + OFF_XP);
    unsigned* slotsX = (unsigned*)(ws + OFF_SL);   // [128]
    unsigned* slotsF = slotsX + 128;               // [64]
    unsigned* slotsB = slotsX + 192;               // [64]

    __shared__ __align__(16) char arena[L_TOTAL];
    unsigned short* whhH = (unsigned short*)(arena + L_WHH_H);
    unsigned short* whhL = (unsigned short*)(arena + L_WHH_L);
    unsigned short* wihH = (unsigned short*)(arena + L_WIH_H);
    unsigned short* wihL = (unsigned short*)(arena + L_WIH_L);
    unsigned short* dwhH = (unsigned short*)(arena + L_DWH_H);
    unsigned short* dwhL = (unsigned short*)(arena + L_DWH_L);
    float* pre = (float*)(arena + L_PRE);

    const int dir = bid >> 6;          // 0 fwd (blocks 0..63), 1 bwd (64..127)
    const int blk = bid & 63;
    const int e0  = blk * 8;           // encoder block owns h dims [e0, e0+8)
    const float* Wih  = dir ? WihB : WihF;
    const float* Whh  = dir ? WhhB : WhhF;
    const float* bias = dir ? bB   : bF;
    unsigned short* ring = dir ? hbR : hfR;

    // ---- init: zero slab 0, NaN-poison slabs 1..512, zero slots ----
    {
        unsigned long long* hf64 = (unsigned long long*)hfR;
        unsigned long long* hb64 = (unsigned long long*)hbR;
        unsigned long long* hd64 = (unsigned long long*)hdR;
        const int gstep = 128 * 512;
        for (int i = bid * 512 + tid; i < 8192; i += gstep) { astore_u64(hf64 + i, 0ull); astore_u64(hb64 + i, 0ull); }
        for (int i = bid * 512 + tid; i < 4096; i += gstep) astore_u64(hd64 + i, 0ull);
        for (int i = 8192 + bid * 512 + tid; i < 4202496; i += gstep) { astore_u64(hf64 + i, NANP); astore_u64(hb64 + i, NANP); }
        for (int i = 4096 + bid * 512 + tid; i < 2101248; i += gstep) astore_u64(hd64 + i, NANP);
        if (bid == 0 && tid < 256) astore_u32(slotsX + tid, 0u);
    }

    // ---- one-time weight conversion fp32 -> bf16 hi/lo in LDS ----
    for (int idx = tid; idx < 32 * 512; idx += 512) {        // Whh 32 rows x 512
        int r = idx >> 9, k = idx & 511;
        int grow = (r >> 3) * E_ + e0 + (r & 7);
        float w0 = Whh[(size_t)grow * E_ + k];
        __bf16 h16 = (__bf16)w0;
        __bf16 l16 = (__bf16)(w0 - (float)h16);
        whhH[r * LDK_H + k] = __builtin_bit_cast(unsigned short, h16);
        whhL[r * LDK_H + k] = __builtin_bit_cast(unsigned short, l16);
    }
    for (int idx = tid; idx < 32 * 256; idx += 512) {        // Wih 32 rows x 256
        int r = idx >> 8, k = idx & 255;
        int grow = (r >> 3) * E_ + e0 + (r & 7);
        float w0 = Wih[(size_t)grow * F_ + k];
        __bf16 h16 = (__bf16)w0;
        __bf16 l16 = (__bf16)(w0 - (float)h16);
        wihH[r * LDK_X + k] = __builtin_bit_cast(unsigned short, h16);
        wihL[r * LDK_X + k] = __builtin_bit_cast(unsigned short, l16);
    }
    if (bid < 64) {                                          // dec Whh 16 rows x 256
        const int fb0 = bid * 4;
        for (int idx = tid; idx < 16 * 256; idx += 512) {
            int r = idx >> 8, k = idx & 255;
            int grow = (r >> 2) * F_ + fb0 + (r & 3);
            float w0 = dWhh[(size_t)grow * F_ + k];
            __bf16 h16 = (__bf16)w0;
            __bf16 l16 = (__bf16)(w0 - (float)h16);
            dwhH[r * LDK_X + k] = __builtin_bit_cast(unsigned short, h16);
            dwhL[r * LDK_X + k] = __builtin_bit_cast(unsigned short, l16);
        }
    }
    __syncthreads();
    grid.sync();   // poison + ring[0] + slots visible everywhere before any poll

    const int w    = tid >> 6;        // wave 0..7
    const int lane = tid & 63;
    const int col  = lane & 15;
    const int quad = lane >> 4;

    // ================= encoder: 4 autonomous batch-group waves =================
    // Waves 0..3: wave nt computes ALL 32 gate rows (both M-tiles, hi/lo) for
    // batches [16nt,16nt+16), private pre column slice, own epilogue + ring
    // store. No barriers in the loop. Waves 4..7 idle.
    // POLL SPLIT: half A (kt 0..7 = producer blocks 0..31) is waited on and
    // consumed (MFMA) while half B (blocks 32..63) stragglers land.
    {
        if (w < 4) {
            const int nt = w;
            const int bcol = nt * 16 + col;
            const unsigned short* aH0h = whhH + col * LDK_H + quad * 8;
            const unsigned short* aH0l = whhL + col * LDK_H + quad * 8;
            const unsigned short* aH1h = whhH + (16 + col) * LDK_H + quad * 8;
            const unsigned short* aH1l = whhL + (16 + col) * LDK_H + quad * 8;
            const unsigned short* aX0h = wihH + col * LDK_X + quad * 8;
            const unsigned short* aX0l = wihL + col * LDK_X + quad * 8;
            const unsigned short* aX1h = wihH + (16 + col) * LDK_X + quad * 8;
            const unsigned short* aX1l = wihL + (16 + col) * LDK_X + quad * 8;

            const unsigned long long* encHp =
                (const unsigned long long*)ring + (size_t)quad * 128 + (size_t)bcol * 2;

            // epilogue: lane owns dims {ej0, ej0+1} of batch eb (within group nt)
            const int colb = lane >> 2;
            const int ej0  = (lane & 3) * 2;
            const int eb   = nt * 16 + colb;
            const float bGi0 = bias[0 * E_ + e0 + ej0], bGi1 = bias[0 * E_ + e0 + ej0 + 1];
            const float bGf0 = bias[1 * E_ + e0 + ej0], bGf1 = bias[1 * E_ + e0 + ej0 + 1];
            const float bGg0 = bias[2 * E_ + e0 + ej0], bGg1 = bias[2 * E_ + e0 + ej0 + 1];
            const float bGo0 = bias[3 * E_ + e0 + ej0], bGo1 = bias[3 * E_ + e0 + ej0 + 1];
            float c0 = 0.0f, c1 = 0.0f;
            unsigned* ringO = (unsigned*)ring;

            for (int t = 0; t < T_; ++t) {
                const int t_eff = dir ? (T_ - 1 - t) : t;

                // ---- x-part (h-independent; fills the produce->consume
                //      latency window — do NOT move or shrink; see R10) ----
                f32x4 xc0 = {0.f, 0.f, 0.f, 0.f};
                f32x4 xd0 = xc0, xc1 = xc0, xd1 = xc0;
                {
                    const float* xrow = seq + (size_t)t_eff * B_ * F_ + bcol * F_ + quad * 8;
                    #pragma unroll
                    for (int kt = 0; kt < 8; ++kt) {
                        float4 v0 = *(const float4*)(xrow + kt * 32);
                        float4 v1 = *(const float4*)(xrow + kt * 32 + 4);
                        float vv[8] = {v0.x, v0.y, v0.z, v0.w, v1.x, v1.y, v1.z, v1.w};
                        bf16x8 xh, xl;
                        #pragma unroll
                        for (int j2 = 0; j2 < 8; ++j2) {
                            __bf16 hvv = (__bf16)vv[j2];
                            xh[j2] = hvv;
                            xl[j2] = (__bf16)(vv[j2] - (float)hvv);
                        }
                        bf16x8 a0h = *(const bf16x8*)(aX0h + kt * 32);
                        bf16x8 a0l = *(const bf16x8*)(aX0l + kt * 32);
                        bf16x8 a1h = *(const bf16x8*)(aX1h + kt * 32);
                        bf16x8 a1l = *(const bf16x8*)(aX1l + kt * 32);
                        xc0 = __builtin_amdgcn_mfma_f32_16x16x32_bf16(a0h, xh, xc0, 0, 0, 0);
                        xd0 = __builtin_amdgcn_mfma_f32_16x16x32_bf16(a0l, xh, xd0, 0, 0, 0);
                        xc0 = __builtin_amdgcn_mfma_f32_16x16x32_bf16(a0h, xl, xc0, 0, 0, 0);
                        xc1 = __builtin_amdgcn_mfma_f32_16x16x32_bf16(a1h, xh, xc1, 0, 0, 0);
                        xd1 = __builtin_amdgcn_mfma_f32_16x16x32_bf16(a1l, xh, xd1, 0, 0, 0);
                        xc1 = __builtin_amdgcn_mfma_f32_16x16x32_bf16(a1h, xl, xc1, 0, 0, 0);
                    }
                }

                const unsigned long long* hpT = encHp + (size_t)t * 8192;
                unsigned long long hv[32];
                f32x4 p00 = xc0 + xd0;        // fold x into hi-chain head
                f32x4 p10 = xc1 + xd1;
                f32x4 p01 = {0.f, 0.f, 0.f, 0.f};
                f32x4 q00 = p01, q01 = p01, q10 = p01, q11 = p01;
                f32x4 p11 = p01;

                // ---- poll half A (kt 0..7 = producer blocks 0..31) ----
                for (;;) {
                    #pragma unroll
                    for (int kt = 0; kt < 8; ++kt) {
                        hv[2 * kt]     = aload_u64(hpT + kt * 512);
                        hv[2 * kt + 1] = aload_u64(hpT + kt * 512 + 1);
                    }
                    unsigned long long m = 0;
                    #pragma unroll
                    for (int i = 0; i < 16; ++i) m |= nanmask(hv[i]);
                    if (!__any(m != 0ull)) break;
                    __builtin_amdgcn_s_sleep(1);
                }
                asm volatile("" ::: "memory");

                // ---- MFMA half A (overlaps half-B straggler wait) ----
                #pragma unroll
                for (int kt = 0; kt < 8; ++kt) {
                    ulonglong2 qv; qv.x = hv[2 * kt]; qv.y = hv[2 * kt + 1];
                    bf16x8 hb = __builtin_bit_cast(bf16x8, qv);
                    p00 = __builtin_amdgcn_mfma_f32_16x16x32_bf16(*(const bf16x8*)(aH0h + kt * 32), hb, p00, 0, 0, 0);
                    q00 = __builtin_amdgcn_mfma_f32_16x16x32_bf16(*(const bf16x8*)(aH0l + kt * 32), hb, q00, 0, 0, 0);
                    p10 = __builtin_amdgcn_mfma_f32_16x16x32_bf16(*(const bf16x8*)(aH1h + kt * 32), hb, p10, 0, 0, 0);
                    q10 = __builtin_amdgcn_mfma_f32_16x16x32_bf16(*(const bf16x8*)(aH1l + kt * 32), hb, q10, 0, 0, 0);
                }

                // ---- poll half B (kt 8..15 = producer blocks 32..63) ----
                for (;;) {
                    #pragma unroll
                    for (int kt = 8; kt < 16; ++kt) {
                        hv[2 * kt]     = aload_u64(hpT + kt * 512);
                        hv[2 * kt + 1] = aload_u64(hpT + kt * 512 + 1);
                    }
                    unsigned long long m = 0;
                    #pragma unroll
                    for (int i = 16; i < 32; ++i) m |= nanmask(hv[i]);
                    if (!__any(m != 0ull)) break;
                    __builtin_amdgcn_s_sleep(1);
                }
                asm volatile("" ::: "memory");

                // ---- MFMA half B ----
                #pragma unroll
                for (int kt = 8; kt < 16; ++kt) {
                    ulonglong2 qv; qv.x = hv[2 * kt]; qv.y = hv[2 * kt + 1];
                    bf16x8 hb = __builtin_bit_cast(bf16x8, qv);
                    p01 = __builtin_amdgcn_mfma_f32_16x16x32_bf16(*(const bf16x8*)(aH0h + kt * 32), hb, p01, 0, 0, 0);
                    q01 = __builtin_amdgcn_mfma_f32_16x16x32_bf16(*(const bf16x8*)(aH0l + kt * 32), hb, q01, 0, 0, 0);
                    p11 = __builtin_amdgcn_mfma_f32_16x16x32_bf16(*(const bf16x8*)(aH1h + kt * 32), hb, p11, 0, 0, 0);
                    q11 = __builtin_amdgcn_mfma_f32_16x16x32_bf16(*(const bf16x8*)(aH1l + kt * 32), hb, q11, 0, 0, 0);
                }
                f32x4 s0 = (p00 + p01) + (q00 + q01);
                f32x4 s1 = (p10 + p11) + (q10 + q11);

                // ---- wave-private dump (column slice nt*16..+16); no barrier ----
                #pragma unroll
                for (int rg = 0; rg < 4; ++rg) {
                    pre[(quad * 4 + rg) * LDP + nt * 16 + col]      = s0[rg];
                    pre[(16 + quad * 4 + rg) * LDP + nt * 16 + col] = s1[rg];
                }
                asm volatile("s_waitcnt lgkmcnt(0)" ::: "memory");
                __builtin_amdgcn_sched_barrier(0);

                // ---- epilogue: 2 h-values per lane ----
                {
                    float gI0 = pre[(0 * 8 + ej0) * LDP + nt * 16 + colb] + bGi0;
                    float gF0 = pre[(1 * 8 + ej0) * LDP + nt * 16 + colb] + bGf0;
                    float gG0 = pre[(2 * 8 + ej0) * LDP + nt * 16 + colb] + bGg0;
                    float gO0 = pre[(3 * 8 + ej0) * LDP + nt * 16 + colb] + bGo0;
                    float gI1 = pre[(0 * 8 + ej0 + 1) * LDP + nt * 16 + colb] + bGi1;
                    float gF1 = pre[(1 * 8 + ej0 + 1) * LDP + nt * 16 + colb] + bGf1;
                    float gG1 = pre[(2 * 8 + ej0 + 1) * LDP + nt * 16 + colb] + bGg1;
                    float gO1 = pre[(3 * 8 + ej0 + 1) * LDP + nt * 16 + colb] + bGo1;
                    c0 = sigmoidf_(gF0) * c0 + sigmoidf_(gI0) * tanhf_(gG0);
                    c1 = sigmoidf_(gF1) * c1 + sigmoidf_(gI1) * tanhf_(gG1);
                    float h0 = sigmoidf_(gO0) * tanhf_(c0);
                    float h1 = sigmoidf_(gO1) * tanhf_(c1);
                    unsigned pk = (unsigned)f2bf(h0) | ((unsigned)f2bf(h1) << 16);
                    astore_u32(ringO + (size_t)(t + 1) * 16384 + blk * 256 + eb * 4 + (lane & 3), pk);
                }
            }
        }
        // one-time end-of-encoder signal (for xp0 join); all 8 waves arrive
        __syncthreads();   // drains working waves' ring stores
        if (tid == 0) astore_u32((dir ? slotsB : slotsF) + blk, 1u);
        // join both directions
        if (tid < 64) {
            bool ok = (aload_u32(slotsF + tid) != 0u) && (aload_u32(slotsB + tid) != 0u);
            while (!__all(ok)) {
                __builtin_amdgcn_s_sleep(4);
                ok = (aload_u32(slotsF + tid) != 0u) && (aload_u32(slotsB + tid) != 0u);
            }
            asm volatile("" ::: "memory");
        }
        __syncthreads();
    }

    // ================= xp0 = [h_f | h_b] @ dec_Wih^T + dec_b =================
    {
        const int r8 = tid >> 6, xb = tid & 63;
        const int r = bid * 8 + r8;                       // 0..1023
        const float* wr = dWih + (size_t)r * (2 * E_);    // wave-uniform row
        float accv = db[r];
        const unsigned long long* hfq = (const unsigned long long*)hfR + (size_t)T_ * 8192 + xb * 2;
        const unsigned long long* hbq = (const unsigned long long*)hbR + (size_t)T_ * 8192 + xb * 2;
        for (int g = 0; g < 64; ++g) {
            unsigned long long v0 = hfq[g * 128], v1 = hfq[g * 128 + 1];
            accv = fmaf(wr[g * 8 + 0], bfbits2f((unsigned)(v0 & 0xffff)), accv);
            accv = fmaf(wr[g * 8 + 1], bfbits2f((unsigned)((v0 >> 16) & 0xffff)), accv);
            accv = fmaf(wr[g * 8 + 2], bfbits2f((unsigned)((v0 >> 32) & 0xffff)), accv);
            accv = fmaf(wr[g * 8 + 3], bfbits2f((unsigned)((v0 >> 48) & 0xffff)), accv);
            accv = fmaf(wr[g * 8 + 4], bfbits2f((unsigned)(v1 & 0xffff)), accv);
            accv = fmaf(wr[g * 8 + 5], bfbits2f((unsigned)((v1 >> 16) & 0xffff)), accv);
            accv = fmaf(wr[g * 8 + 6], bfbits2f((unsigned)((v1 >> 32) & 0xffff)), accv);
            accv = fmaf(wr[g * 8 + 7], bfbits2f((unsigned)((v1 >> 48) & 0xffff)), accv);
        }
        for (int g = 0; g < 64; ++g) {
            unsigned long long v0 = hbq[g * 128], v1 = hbq[g * 128 + 1];
            accv = fmaf(wr[E_ + g * 8 + 0], bfbits2f((unsigned)(v0 & 0xffff)), accv);
            accv = fmaf(wr[E_ + g * 8 + 1], bfbits2f((unsigned)((v0 >> 16) & 0xffff)), accv);
            accv = fmaf(wr[E_ + g * 8 + 2], bfbits2f((unsigned)((v0 >> 32) & 0xffff)), accv);
            accv = fmaf(wr[E_ + g * 8 + 3], bfbits2f((unsigned)((v0 >> 48) & 0xffff)), accv);
            accv = fmaf(wr[E_ + g * 8 + 4], bfbits2f((unsigned)(v1 & 0xffff)), accv);
            accv = fmaf(wr[E_ + g * 8 + 5], bfbits2f((unsigned)((v1 >> 16) & 0xffff)), accv);
            accv = fmaf(wr[E_ + g * 8 + 6], bfbits2f((unsigned)((v1 >> 32) & 0xffff)), accv);
            accv = fmaf(wr[E_ + g * 8 + 7], bfbits2f((unsigned)((v1 >> 48) & 0xffff)), accv);
        }
        astore_f(&xp0T[r * B_ + xb], accv);
        __syncthreads();         // drain all waves' xp0 stores
        if (tid == 0) astore_u32(slotsX + bid, 1u);
        if (bid >= 64) return;
        if (tid < 64) {
            bool ok = (aload_u32(slotsX + tid) != 0u) && (aload_u32(slotsX + 64 + tid) != 0u);
            while (!__all(ok)) {
                __builtin_amdgcn_s_sleep(4);
                ok = (aload_u32(slotsX + tid) != 0u) && (aload_u32(slotsX + 64 + tid) != 0u);
            }
            asm volatile("" ::: "memory");
        }
        __syncthreads();
    }

    // ================= decoder: 64 blocks x 4 f-dims (MFMA) =================
    // R6 kh-split: each wave polls HALF the producers (parallel straggler
    // waits on different SIMDs), joined by barrier B; barrier C protects pre
    // from next-iteration overwrites (REQUIRED — learned in R8).
    {
        const int fb0 = bid * 4;
        const int ntD = w & 3, kh = w >> 2;      // N-tile, K-half per wave
        const int bcolD = ntD * 16 + col;
        const unsigned short* aDh = dwhH + col * LDK_X + kh * 128 + quad * 8;
        const unsigned short* aDl = dwhL + col * LDK_X + kh * 128 + quad * 8;

        // consumer frag base: u64 units. g0 = kh*32 + kt*8 + quad*2;
        const unsigned long long* decHp =
            (const unsigned long long*)hdR + (size_t)(kh * 32 + quad * 2) * 64 + bcolD;
        unsigned* hdO = (unsigned*)hdR;

        const int ej = tid & 3, eb = tid >> 2;   // epilogue (j,b) for tid<256
        float xg0 = 0, xg1 = 0, xg2 = 0, xg3 = 0;
        if (tid < 256) {
            xg0 = xp0T[(0 * F_ + fb0 + ej) * B_ + eb];
            xg1 = xp0T[(1 * F_ + fb0 + ej) * B_ + eb];
            xg2 = xp0T[(2 * F_ + fb0 + ej) * B_ + eb];
            xg3 = xp0T[(3 * F_ + fb0 + ej) * B_ + eb];
        }
        float creg = 0.0f;

        for (int t = 0; t < T_; ++t) {
            // ---- poll-load h_t frags (plain full reload) ----
            unsigned long long hv[8];
            {
                const unsigned long long* hpT = decHp + (size_t)t * 4096;
                for (;;) {
                    #pragma unroll
                    for (int kt = 0; kt < 4; ++kt) {
                        hv[2 * kt]     = aload_u64(hpT + kt * 512);
                        hv[2 * kt + 1] = aload_u64(hpT + kt * 512 + 64);
                    }
                    unsigned long long m = 0;
                    #pragma unroll
                    for (int i = 0; i < 8; ++i) m |= nanmask(hv[i]);
                    if (!__any(m != 0ull)) break;
                    __builtin_amdgcn_s_sleep(1);
                }
                asm volatile("" ::: "memory");
            }

            f32x4 accA = {0.f, 0.f, 0.f, 0.f};
            f32x4 accB = accA;
            #pragma unroll
            for (int kt = 0; kt < 4; ++kt) {
                ulonglong2 q; q.x = hv[2 * kt]; q.y = hv[2 * kt + 1];
                bf16x8 hb = __builtin_bit_cast(bf16x8, q);
                bf16x8 ah = *(const bf16x8*)(aDh + kt * 32);
                bf16x8 al = *(const bf16x8*)(aDl + kt * 32);
                accA = __builtin_amdgcn_mfma_f32_16x16x32_bf16(ah, hb, accA, 0, 0, 0);
                accB = __builtin_amdgcn_mfma_f32_16x16x32_bf16(al, hb, accB, 0, 0, 0);
            }
            {
                f32x4 s = accA + accB;
                #pragma unroll
                for (int rg = 0; rg < 4; ++rg)
                    pre[kh * (16 * LDP) + (quad * 4 + rg) * LDP + ntD * 16 + col] = s[rg];
            }
            asm volatile("s_waitcnt lgkmcnt(0)" ::: "memory");
            __builtin_amdgcn_sched_barrier(0);
            __builtin_amdgcn_s_barrier();        // barrier B: pre complete

            if (tid < 256) {
                float gI = pre[(0 * 4 + ej) * LDP + eb] + pre[16 * LDP + (0 * 4 + ej) * LDP + eb] + xg0;
                float gF = pre[(1 * 4 + ej) * LDP + eb] + pre[16 * LDP + (1 * 4 + ej) * LDP + eb] + xg1;
                float gG = pre[(2 * 4 + ej) * LDP + eb] + pre[16 * LDP + (2 * 4 + ej) * LDP + eb] + xg2;
                float gO = pre[(3 * 4 + ej) * LDP + eb] + pre[16 * LDP + (3 * 4 + ej) * LDP + eb] + xg3;
                creg = sigmoidf_(gF) * creg + sigmoidf_(gI) * tanhf_(gG);
                float h = sigmoidf_(gO) * tanhf_(creg);
                unsigned hb16 = (unsigned)f2bf(h);
                unsigned hN = __shfl_down(hb16, 1);
                if ((ej & 1) == 0) {
                    astore_u32(hdO + (size_t)(t + 1) * 8192 + bid * 128 + eb * 2 + (ej >> 1),
                               hb16 | (hN << 16));
                }
                out[(size_t)t * B_ * F_ + (size_t)eb * F_ + fb0 + ej] = h;
            }
            asm volatile("" ::: "memory");
            __builtin_amdgcn_s_barrier();        // barrier C: protect pre reuse
            asm volatile("" ::: "memory");
        }
    }
}

extern "C" void kernel_launch(void* const* d_in, const int* in_sizes, int n_in,
                              void* d_out, int out_size, void* d_ws, size_t ws_size,
                              hipStream_t stream) {
    const float* seq  = (const float*)d_in[0];
    const float* WihF = (const float*)d_in[1];
    const float* WhhF = (const float*)d_in[2];
    const float* bF   = (const float*)d_in[3];
    const float* WihB = (const float*)d_in[4];
    const float* WhhB = (const float*)d_in[5];
    const float* bB   = (const float*)d_in[6];
    const float* dWih = (const float*)d_in[7];
    const float* dWhh = (const float*)d_in[8];
    const float* db   = (const float*)d_in[9];
    float* out = (float*)d_out;
    char* ws   = (char*)d_ws;

    void* args[] = { &seq, &WihF, &WhhF, &bF, &WihB, &WhhB, &bB,
                     &dWih, &dWhh, &db, &out, &ws };
    hipLaunchCooperativeKernel((void*)autoenc_kernel, dim3(128), dim3(512),
                               args, 0, stream);
}

// Round 12
// 3696.571 us; speedup vs baseline: 1.1664x; 1.1364x over previous
//
#include <hip/hip_runtime.h>
#include <hip/hip_cooperative_groups.h>

namespace cg = cooperative_groups;

#define T_  512
#define B_  64
#define F_  256
#define E_  512
#define AGENT __HIP_MEMORY_SCOPE_AGENT

typedef __bf16 bf16x8 __attribute__((ext_vector_type(8)));
typedef float  f32x4  __attribute__((ext_vector_type(4)));

// ---- ws layout (bytes). Write-once rings; DATA IS THE SIGNAL:
// rings pre-poisoned with bf16 NaN (0x7FC0). h = sigmoid*tanh in (-1,1)
// never rounds to NaN, so consumers poll the data itself with agent-scope
// loads until every bf16 half is non-NaN.
// Layout: enc ring[t][g=e>>3][b][8 dims] bf16, dec ring[t][g=f>>2][b][4] bf16
//
// Structure notes (falsified alternatives, R7-R11):
//  - x-part BEFORE poll is load-bearing: it fills the producer store->L3
//    visibility window; removing/offloading it causes premature-poll retry
//    storms (R10: +16%, FETCH +200MB).
//  - Encoder poll must be ONE batched 32-u64 load round (R11 split: +13%).
//  - Plain full reload in retry loop (R9 selective: +11%, FETCH unchanged).
//  - Decoder kh-split + 2 barriers is optimal (R7 autonomy: +8%; R8 showed
//    barrier C is required for correctness under kh-split).
#define OFF_HF   0ull                    // [513][64][64][8] bf16 = 33,619,968
#define OFF_HB   33619968ull             // same
#define OFF_HD   67239936ull             // [513][64][64][4] bf16 = 16,809,984
#define OFF_XP   84049920ull             // [4F][B] f32 = 262,144
#define OFF_SL   84312064ull             // slotsX[128], slotsF[64], slotsB[64]

// ---- LDS arena (bytes); weights live here for the whole kernel ----
#define L_WHH_H 0        // ushort[32][520]
#define L_WHH_L 33280
#define L_WIH_H 66560    // ushort[32][264]
#define L_WIH_L 83456
#define L_DWH_H 100352   // ushort[16][264]
#define L_DWH_L 108800
#define L_PRE   117248   // float[32][68]
#define L_TOTAL 125952
#define LDK_H 520        // whh lds row stride (ushorts)
#define LDK_X 264        // wih/dwhh stride
#define LDP   68         // pre row stride (floats)

#define NANP 0x7fc07fc07fc07fc0ull
#define K1_  0x0001000100010001ull
#define K8_  0x8000800080008000ull

__device__ __forceinline__ float sigmoidf_(float x) {
    return __builtin_amdgcn_rcpf(1.0f + __expf(-x));
}
__device__ __forceinline__ float tanhf_(float x) {
    return 1.0f - 2.0f * __builtin_amdgcn_rcpf(1.0f + __expf(2.0f * x));
}
__device__ __forceinline__ unsigned short f2bf(float f) {   // RNE
    unsigned u = __float_as_uint(f);
    u += 0x7fffu + ((u >> 16) & 1u);
    return (unsigned short)(u >> 16);
}
__device__ __forceinline__ float bfbits2f(unsigned us) {
    return __uint_as_float(us << 16);
}
__device__ __forceinline__ void astore_u32(unsigned* p, unsigned v) {
    __hip_atomic_store(p, v, __ATOMIC_RELAXED, AGENT);
}
__device__ __forceinline__ unsigned aload_u32(const unsigned* p) {
    return __hip_atomic_load(p, __ATOMIC_RELAXED, AGENT);
}
__device__ __forceinline__ void astore_u64(unsigned long long* p, unsigned long long v) {
    __hip_atomic_store(p, v, __ATOMIC_RELAXED, AGENT);
}
__device__ __forceinline__ unsigned long long aload_u64(const unsigned long long* p) {
    return __hip_atomic_load(p, __ATOMIC_RELAXED, AGENT);
}
__device__ __forceinline__ void astore_f(float* p, float v) {
    __hip_atomic_store(p, v, __ATOMIC_RELAXED, AGENT);
}
// any 16-bit half of v equal to bf16 NaN 0x7fc0?
__device__ __forceinline__ unsigned long long nanmask(unsigned long long v) {
    unsigned long long x = v ^ NANP;
    return (x - K1_) & ~x & K8_;
}

__global__ __launch_bounds__(512, 2)
void autoenc_kernel(const float* __restrict__ seq,
                    const float* __restrict__ WihF, const float* __restrict__ WhhF, const float* __restrict__ bF,
                    const float* __restrict__ WihB, const float* __restrict__ WhhB, const float* __restrict__ bB,
                    const float* __restrict__ dWih, const float* __restrict__ dWhh, const float* __restrict__ db,
                    float* __restrict__ out, char* __restrict__ ws)
{
    cg::grid_group grid = cg::this_grid();
    const int tid = threadIdx.x;
    const int bid = blockIdx.x;

    unsigned short* hfR = (unsigned short*)(ws + OFF_HF);
    unsigned short* hbR = (unsigned short*)(ws + OFF_HB);
    unsigned short* hdR = (unsigned short*)(ws + OFF_HD);
    float* xp0T = (float*)(ws + OFF_XP);
    unsigned* slotsX = (unsigned*)(ws + OFF_SL);   // [128]
    unsigned* slotsF = slotsX + 128;               // [64]
    unsigned* slotsB = slotsX + 192;               // [64]

    __shared__ __align__(16) char arena[L_TOTAL];
    unsigned short* whhH = (unsigned short*)(arena + L_WHH_H);
    unsigned short* whhL = (unsigned short*)(arena + L_WHH_L);
    unsigned short* wihH = (unsigned short*)(arena + L_WIH_H);
    unsigned short* wihL = (unsigned short*)(arena + L_WIH_L);
    unsigned short* dwhH = (unsigned short*)(arena + L_DWH_H);
    unsigned short* dwhL = (unsigned short*)(arena + L_DWH_L);
    float* pre = (float*)(arena + L_PRE);

    const int dir = bid >> 6;          // 0 fwd (blocks 0..63), 1 bwd (64..127)
    const int blk = bid & 63;
    const int e0  = blk * 8;           // encoder block owns h dims [e0, e0+8)
    const float* Wih  = dir ? WihB : WihF;
    const float* Whh  = dir ? WhhB : WhhF;
    const float* bias = dir ? bB   : bF;
    unsigned short* ring = dir ? hbR : hfR;

    // ---- init: zero slab 0, NaN-poison slabs 1..512, zero slots ----
    {
        unsigned long long* hf64 = (unsigned long long*)hfR;
        unsigned long long* hb64 = (unsigned long long*)hbR;
        unsigned long long* hd64 = (unsigned long long*)hdR;
        const int gstep = 128 * 512;
        for (int i = bid * 512 + tid; i < 8192; i += gstep) { astore_u64(hf64 + i, 0ull); astore_u64(hb64 + i, 0ull); }
        for (int i = bid * 512 + tid; i < 4096; i += gstep) astore_u64(hd64 + i, 0ull);
        for (int i = 8192 + bid * 512 + tid; i < 4202496; i += gstep) { astore_u64(hf64 + i, NANP); astore_u64(hb64 + i, NANP); }
        for (int i = 4096 + bid * 512 + tid; i < 2101248; i += gstep) astore_u64(hd64 + i, NANP);
        if (bid == 0 && tid < 256) astore_u32(slotsX + tid, 0u);
    }

    // ---- one-time weight conversion fp32 -> bf16 hi/lo in LDS ----
    for (int idx = tid; idx < 32 * 512; idx += 512) {        // Whh 32 rows x 512
        int r = idx >> 9, k = idx & 511;
        int grow = (r >> 3) * E_ + e0 + (r & 7);
        float w0 = Whh[(size_t)grow * E_ + k];
        __bf16 h16 = (__bf16)w0;
        __bf16 l16 = (__bf16)(w0 - (float)h16);
        whhH[r * LDK_H + k] = __builtin_bit_cast(unsigned short, h16);
        whhL[r * LDK_H + k] = __builtin_bit_cast(unsigned short, l16);
    }
    for (int idx = tid; idx < 32 * 256; idx += 512) {        // Wih 32 rows x 256
        int r = idx >> 8, k = idx & 255;
        int grow = (r >> 3) * E_ + e0 + (r & 7);
        float w0 = Wih[(size_t)grow * F_ + k];
        __bf16 h16 = (__bf16)w0;
        __bf16 l16 = (__bf16)(w0 - (float)h16);
        wihH[r * LDK_X + k] = __builtin_bit_cast(unsigned short, h16);
        wihL[r * LDK_X + k] = __builtin_bit_cast(unsigned short, l16);
    }
    if (bid < 64) {                                          // dec Whh 16 rows x 256
        const int fb0 = bid * 4;
        for (int idx = tid; idx < 16 * 256; idx += 512) {
            int r = idx >> 8, k = idx & 255;
            int grow = (r >> 2) * F_ + fb0 + (r & 3);
            float w0 = dWhh[(size_t)grow * F_ + k];
            __bf16 h16 = (__bf16)w0;
            __bf16 l16 = (__bf16)(w0 - (float)h16);
            dwhH[r * LDK_X + k] = __builtin_bit_cast(unsigned short, h16);
            dwhL[r * LDK_X + k] = __builtin_bit_cast(unsigned short, l16);
        }
    }
    __syncthreads();
    grid.sync();   // poison + ring[0] + slots visible everywhere before any poll

    const int w    = tid >> 6;        // wave 0..7
    const int lane = tid & 63;
    const int col  = lane & 15;
    const int quad = lane >> 4;

    // ================= encoder: 4 autonomous batch-group waves =================
    // Waves 0..3: wave nt computes ALL 32 gate rows (both M-tiles, hi/lo) for
    // batches [16nt,16nt+16), keeps a private pre column slice, runs its own
    // epilogue and ring store. No barriers in the loop. Waves 4..7 idle.
    {
        if (w < 4) {
            const int nt = w;
            const int bcol = nt * 16 + col;
            const unsigned short* aH0h = whhH + col * LDK_H + quad * 8;
            const unsigned short* aH0l = whhL + col * LDK_H + quad * 8;
            const unsigned short* aH1h = whhH + (16 + col) * LDK_H + quad * 8;
            const unsigned short* aH1l = whhL + (16 + col) * LDK_H + quad * 8;
            const unsigned short* aX0h = wihH + col * LDK_X + quad * 8;
            const unsigned short* aX0l = wihL + col * LDK_X + quad * 8;
            const unsigned short* aX1h = wihH + (16 + col) * LDK_X + quad * 8;
            const unsigned short* aX1l = wihL + (16 + col) * LDK_X + quad * 8;

            const unsigned long long* encHp =
                (const unsigned long long*)ring + (size_t)quad * 128 + (size_t)bcol * 2;

            // epilogue: lane owns dims {ej0, ej0+1} of batch eb (within group nt)
            const int colb = lane >> 2;
            const int ej0  = (lane & 3) * 2;
            const int eb   = nt * 16 + colb;
            const float bGi0 = bias[0 * E_ + e0 + ej0], bGi1 = bias[0 * E_ + e0 + ej0 + 1];
            const float bGf0 = bias[1 * E_ + e0 + ej0], bGf1 = bias[1 * E_ + e0 + ej0 + 1];
            const float bGg0 = bias[2 * E_ + e0 + ej0], bGg1 = bias[2 * E_ + e0 + ej0 + 1];
            const float bGo0 = bias[3 * E_ + e0 + ej0], bGo1 = bias[3 * E_ + e0 + ej0 + 1];
            float c0 = 0.0f, c1 = 0.0f;
            unsigned* ringO = (unsigned*)ring;

            for (int t = 0; t < T_; ++t) {
                const int t_eff = dir ? (T_ - 1 - t) : t;

                // ---- x-part (h-independent; fills produce->consume latency
                //      window — load-bearing, do not move/shrink: R10) ----
                f32x4 xc0 = {0.f, 0.f, 0.f, 0.f};
                f32x4 xd0 = xc0, xc1 = xc0, xd1 = xc0;
                {
                    const float* xrow = seq + (size_t)t_eff * B_ * F_ + bcol * F_ + quad * 8;
                    #pragma unroll
                    for (int kt = 0; kt < 8; ++kt) {
                        float4 v0 = *(const float4*)(xrow + kt * 32);
                        float4 v1 = *(const float4*)(xrow + kt * 32 + 4);
                        float vv[8] = {v0.x, v0.y, v0.z, v0.w, v1.x, v1.y, v1.z, v1.w};
                        bf16x8 xh, xl;
                        #pragma unroll
                        for (int j2 = 0; j2 < 8; ++j2) {
                            __bf16 hvv = (__bf16)vv[j2];
                            xh[j2] = hvv;
                            xl[j2] = (__bf16)(vv[j2] - (float)hvv);
                        }
                        bf16x8 a0h = *(const bf16x8*)(aX0h + kt * 32);
                        bf16x8 a0l = *(const bf16x8*)(aX0l + kt * 32);
                        bf16x8 a1h = *(const bf16x8*)(aX1h + kt * 32);
                        bf16x8 a1l = *(const bf16x8*)(aX1l + kt * 32);
                        xc0 = __builtin_amdgcn_mfma_f32_16x16x32_bf16(a0h, xh, xc0, 0, 0, 0);
                        xd0 = __builtin_amdgcn_mfma_f32_16x16x32_bf16(a0l, xh, xd0, 0, 0, 0);
                        xc0 = __builtin_amdgcn_mfma_f32_16x16x32_bf16(a0h, xl, xc0, 0, 0, 0);
                        xc1 = __builtin_amdgcn_mfma_f32_16x16x32_bf16(a1h, xh, xc1, 0, 0, 0);
                        xd1 = __builtin_amdgcn_mfma_f32_16x16x32_bf16(a1l, xh, xd1, 0, 0, 0);
                        xc1 = __builtin_amdgcn_mfma_f32_16x16x32_bf16(a1h, xl, xc1, 0, 0, 0);
                    }
                }

                // ---- poll h_t (AFTER x-part; ONE batched load round — R11) ----
                unsigned long long hv[32];
                {
                    const unsigned long long* hpT = encHp + (size_t)t * 8192;
                    for (;;) {
                        #pragma unroll
                        for (int kt = 0; kt < 16; ++kt) {
                            hv[2 * kt]     = aload_u64(hpT + kt * 512);
                            hv[2 * kt + 1] = aload_u64(hpT + kt * 512 + 1);
                        }
                        unsigned long long m = 0;
                        #pragma unroll
                        for (int i = 0; i < 32; ++i) m |= nanmask(hv[i]);
                        if (!__any(m != 0ull)) break;
                        __builtin_amdgcn_s_sleep(1);
                    }
                    asm volatile("" ::: "memory");
                }

                // ---- h-part MFMA: 2 M-tiles x hi/lo x 2 K-half chains ----
                f32x4 p00 = {0.f, 0.f, 0.f, 0.f};
                f32x4 p01 = p00, q00 = p00, q01 = p00;
                f32x4 p10 = p00, p11 = p00, q10 = p00, q11 = p00;
                #pragma unroll
                for (int kt = 0; kt < 8; ++kt) {
                    ulonglong2 qv; qv.x = hv[2 * kt]; qv.y = hv[2 * kt + 1];
                    bf16x8 hb = __builtin_bit_cast(bf16x8, qv);
                    p00 = __builtin_amdgcn_mfma_f32_16x16x32_bf16(*(const bf16x8*)(aH0h + kt * 32), hb, p00, 0, 0, 0);
                    q00 = __builtin_amdgcn_mfma_f32_16x16x32_bf16(*(const bf16x8*)(aH0l + kt * 32), hb, q00, 0, 0, 0);
                    p10 = __builtin_amdgcn_mfma_f32_16x16x32_bf16(*(const bf16x8*)(aH1h + kt * 32), hb, p10, 0, 0, 0);
                    q10 = __builtin_amdgcn_mfma_f32_16x16x32_bf16(*(const bf16x8*)(aH1l + kt * 32), hb, q10, 0, 0, 0);
                }
                #pragma unroll
                for (int kt = 8; kt < 16; ++kt) {
                    ulonglong2 qv; qv.x = hv[2 * kt]; qv.y = hv[2 * kt + 1];
                    bf16x8 hb = __builtin_bit_cast(bf16x8, qv);
                    p01 = __builtin_amdgcn_mfma_f32_16x16x32_bf16(*(const bf16x8*)(aH0h + kt * 32), hb, p01, 0, 0, 0);
                    q01 = __builtin_amdgcn_mfma_f32_16x16x32_bf16(*(const bf16x8*)(aH0l + kt * 32), hb, q01, 0, 0, 0);
                    p11 = __builtin_amdgcn_mfma_f32_16x16x32_bf16(*(const bf16x8*)(aH1h + kt * 32), hb, p11, 0, 0, 0);
                    q11 = __builtin_amdgcn_mfma_f32_16x16x32_bf16(*(const bf16x8*)(aH1l + kt * 32), hb, q11, 0, 0, 0);
                }
                f32x4 s0 = ((p00 + p01) + (q00 + q01)) + (xc0 + xd0);
                f32x4 s1 = ((p10 + p11) + (q10 + q11)) + (xc1 + xd1);

                // ---- wave-private dump (column slice nt*16..+16); no barrier ----
                #pragma unroll
                for (int rg = 0; rg < 4; ++rg) {
                    pre[(quad * 4 + rg) * LDP + nt * 16 + col]      = s0[rg];
                    pre[(16 + quad * 4 + rg) * LDP + nt * 16 + col] = s1[rg];
                }
                asm volatile("s_waitcnt lgkmcnt(0)" ::: "memory");
                __builtin_amdgcn_sched_barrier(0);

                // ---- epilogue: 2 h-values per lane ----
                {
                    float gI0 = pre[(0 * 8 + ej0) * LDP + nt * 16 + colb] + bGi0;
                    float gF0 = pre[(1 * 8 + ej0) * LDP + nt * 16 + colb] + bGf0;
                    float gG0 = pre[(2 * 8 + ej0) * LDP + nt * 16 + colb] + bGg0;
                    float gO0 = pre[(3 * 8 + ej0) * LDP + nt * 16 + colb] + bGo0;
                    float gI1 = pre[(0 * 8 + ej0 + 1) * LDP + nt * 16 + colb] + bGi1;
                    float gF1 = pre[(1 * 8 + ej0 + 1) * LDP + nt * 16 + colb] + bGf1;
                    float gG1 = pre[(2 * 8 + ej0 + 1) * LDP + nt * 16 + colb] + bGg1;
                    float gO1 = pre[(3 * 8 + ej0 + 1) * LDP + nt * 16 + colb] + bGo1;
                    c0 = sigmoidf_(gF0) * c0 + sigmoidf_(gI0) * tanhf_(gG0);
                    c1 = sigmoidf_(gF1) * c1 + sigmoidf_(gI1) * tanhf_(gG1);
                    float h0 = sigmoidf_(gO0) * tanhf_(c0);
                    float h1 = sigmoidf_(gO1) * tanhf_(c1);
                    unsigned pk = (unsigned)f2bf(h0) | ((unsigned)f2bf(h1) << 16);
                    astore_u32(ringO + (size_t)(t + 1) * 16384 + blk * 256 + eb * 4 + (lane & 3), pk);
                }
            }
        }
        // one-time end-of-encoder signal (for xp0 join); all 8 waves arrive
        __syncthreads();   // drains working waves' ring stores
        if (tid == 0) astore_u32((dir ? slotsB : slotsF) + blk, 1u);
        // join both directions
        if (tid < 64) {
            bool ok = (aload_u32(slotsF + tid) != 0u) && (aload_u32(slotsB + tid) != 0u);
            while (!__all(ok)) {
                __builtin_amdgcn_s_sleep(4);
                ok = (aload_u32(slotsF + tid) != 0u) && (aload_u32(slotsB + tid) != 0u);
            }
            asm volatile("" ::: "memory");
        }
        __syncthreads();
    }

    // ================= xp0 = [h_f | h_b] @ dec_Wih^T + dec_b =================
    {
        const int r8 = tid >> 6, xb = tid & 63;
        const int r = bid * 8 + r8;                       // 0..1023
        const float* wr = dWih + (size_t)r * (2 * E_);    // wave-uniform row
        float accv = db[r];
        const unsigned long long* hfq = (const unsigned long long*)hfR + (size_t)T_ * 8192 + xb * 2;
        const unsigned long long* hbq = (const unsigned long long*)hbR + (size_t)T_ * 8192 + xb * 2;
        for (int g = 0; g < 64; ++g) {
            unsigned long long v0 = hfq[g * 128], v1 = hfq[g * 128 + 1];
            accv = fmaf(wr[g * 8 + 0], bfbits2f((unsigned)(v0 & 0xffff)), accv);
            accv = fmaf(wr[g * 8 + 1], bfbits2f((unsigned)((v0 >> 16) & 0xffff)), accv);
            accv = fmaf(wr[g * 8 + 2], bfbits2f((unsigned)((v0 >> 32) & 0xffff)), accv);
            accv = fmaf(wr[g * 8 + 3], bfbits2f((unsigned)((v0 >> 48) & 0xffff)), accv);
            accv = fmaf(wr[g * 8 + 4], bfbits2f((unsigned)(v1 & 0xffff)), accv);
            accv = fmaf(wr[g * 8 + 5], bfbits2f((unsigned)((v1 >> 16) & 0xffff)), accv);
            accv = fmaf(wr[g * 8 + 6], bfbits2f((unsigned)((v1 >> 32) & 0xffff)), accv);
            accv = fmaf(wr[g * 8 + 7], bfbits2f((unsigned)((v1 >> 48) & 0xffff)), accv);
        }
        for (int g = 0; g < 64; ++g) {
            unsigned long long v0 = hbq[g * 128], v1 = hbq[g * 128 + 1];
            accv = fmaf(wr[E_ + g * 8 + 0], bfbits2f((unsigned)(v0 & 0xffff)), accv);
            accv = fmaf(wr[E_ + g * 8 + 1], bfbits2f((unsigned)((v0 >> 16) & 0xffff)), accv);
            accv = fmaf(wr[E_ + g * 8 + 2], bfbits2f((unsigned)((v0 >> 32) & 0xffff)), accv);
            accv = fmaf(wr[E_ + g * 8 + 3], bfbits2f((unsigned)((v0 >> 48) & 0xffff)), accv);
            accv = fmaf(wr[E_ + g * 8 + 4], bfbits2f((unsigned)(v1 & 0xffff)), accv);
            accv = fmaf(wr[E_ + g * 8 + 5], bfbits2f((unsigned)((v1 >> 16) & 0xffff)), accv);
            accv = fmaf(wr[E_ + g * 8 + 6], bfbits2f((unsigned)((v1 >> 32) & 0xffff)), accv);
            accv = fmaf(wr[E_ + g * 8 + 7], bfbits2f((unsigned)((v1 >> 48) & 0xffff)), accv);
        }
        astore_f(&xp0T[r * B_ + xb], accv);
        __syncthreads();         // drain all waves' xp0 stores
        if (tid == 0) astore_u32(slotsX + bid, 1u);
        if (bid >= 64) return;
        if (tid < 64) {
            bool ok = (aload_u32(slotsX + tid) != 0u) && (aload_u32(slotsX + 64 + tid) != 0u);
            while (!__all(ok)) {
                __builtin_amdgcn_s_sleep(4);
                ok = (aload_u32(slotsX + tid) != 0u) && (aload_u32(slotsX + 64 + tid) != 0u);
            }
            asm volatile("" ::: "memory");
        }
        __syncthreads();
    }

    // ================= decoder: 64 blocks x 4 f-dims (MFMA) =================
    // R6 kh-split: each wave polls HALF the producers (parallel straggler
    // waits on different SIMDs), joined by barrier B; barrier C protects pre
    // from next-iteration overwrites (REQUIRED — R8).
    {
        const int fb0 = bid * 4;
        const int ntD = w & 3, kh = w >> 2;      // N-tile, K-half per wave
        const int bcolD = ntD * 16 + col;
        const unsigned short* aDh = dwhH + col * LDK_X + kh * 128 + quad * 8;
        const unsigned short* aDl = dwhL + col * LDK_X + kh * 128 + quad * 8;

        // consumer frag base: u64 units. g0 = kh*32 + kt*8 + quad*2;
        const unsigned long long* decHp =
            (const unsigned long long*)hdR + (size_t)(kh * 32 + quad * 2) * 64 + bcolD;
        unsigned* hdO = (unsigned*)hdR;

        const int ej = tid & 3, eb = tid >> 2;   // epilogue (j,b) for tid<256
        float xg0 = 0, xg1 = 0, xg2 = 0, xg3 = 0;
        if (tid < 256) {
            xg0 = xp0T[(0 * F_ + fb0 + ej) * B_ + eb];
            xg1 = xp0T[(1 * F_ + fb0 + ej) * B_ + eb];
            xg2 = xp0T[(2 * F_ + fb0 + ej) * B_ + eb];
            xg3 = xp0T[(3 * F_ + fb0 + ej) * B_ + eb];
        }
        float creg = 0.0f;

        for (int t = 0; t < T_; ++t) {
            // ---- poll-load h_t frags (plain full reload) ----
            unsigned long long hv[8];
            {
                const unsigned long long* hpT = decHp + (size_t)t * 4096;
                for (;;) {
                    #pragma unroll
                    for (int kt = 0; kt < 4; ++kt) {
                        hv[2 * kt]     = aload_u64(hpT + kt * 512);
                        hv[2 * kt + 1] = aload_u64(hpT + kt * 512 + 64);
                    }
                    unsigned long long m = 0;
                    #pragma unroll
                    for (int i = 0; i < 8; ++i) m |= nanmask(hv[i]);
                    if (!__any(m != 0ull)) break;
                    __builtin_amdgcn_s_sleep(1);
                }
                asm volatile("" ::: "memory");
            }

            f32x4 accA = {0.f, 0.f, 0.f, 0.f};
            f32x4 accB = accA;
            #pragma unroll
            for (int kt = 0; kt < 4; ++kt) {
                ulonglong2 q; q.x = hv[2 * kt]; q.y = hv[2 * kt + 1];
                bf16x8 hb = __builtin_bit_cast(bf16x8, q);
                bf16x8 ah = *(const bf16x8*)(aDh + kt * 32);
                bf16x8 al = *(const bf16x8*)(aDl + kt * 32);
                accA = __builtin_amdgcn_mfma_f32_16x16x32_bf16(ah, hb, accA, 0, 0, 0);
                accB = __builtin_amdgcn_mfma_f32_16x16x32_bf16(al, hb, accB, 0, 0, 0);
            }
            {
                f32x4 s = accA + accB;
                #pragma unroll
                for (int rg = 0; rg < 4; ++rg)
                    pre[kh * (16 * LDP) + (quad * 4 + rg) * LDP + ntD * 16 + col] = s[rg];
            }
            asm volatile("s_waitcnt lgkmcnt(0)" ::: "memory");
            __builtin_amdgcn_sched_barrier(0);
            __builtin_amdgcn_s_barrier();        // barrier B: pre complete

            if (tid < 256) {
                float gI = pre[(0 * 4 + ej) * LDP + eb] + pre[16 * LDP + (0 * 4 + ej) * LDP + eb] + xg0;
                float gF = pre[(1 * 4 + ej) * LDP + eb] + pre[16 * LDP + (1 * 4 + ej) * LDP + eb] + xg1;
                float gG = pre[(2 * 4 + ej) * LDP + eb] + pre[16 * LDP + (2 * 4 + ej) * LDP + eb] + xg2;
                float gO = pre[(3 * 4 + ej) * LDP + eb] + pre[16 * LDP + (3 * 4 + ej) * LDP + eb] + xg3;
                creg = sigmoidf_(gF) * creg + sigmoidf_(gI) * tanhf_(gG);
                float h = sigmoidf_(gO) * tanhf_(creg);
                unsigned hb16 = (unsigned)f2bf(h);
                unsigned hN = __shfl_down(hb16, 1);
                if ((ej & 1) == 0) {
                    astore_u32(hdO + (size_t)(t + 1) * 8192 + bid * 128 + eb * 2 + (ej >> 1),
                               hb16 | (hN << 16));
                }
                out[(size_t)t * B_ * F_ + (size_t)eb * F_ + fb0 + ej] = h;
            }
            asm volatile("" ::: "memory");
            __builtin_amdgcn_s_barrier();        // barrier C: protect pre reuse
            asm volatile("" ::: "memory");
        }
    }
}

extern "C" void kernel_launch(void* const* d_in, const int* in_sizes, int n_in,
                              void* d_out, int out_size, void* d_ws, size_t ws_size,
                              hipStream_t stream) {
    const float* seq  = (const float*)d_in[0];
    const float* WihF = (const float*)d_in[1];
    const float* WhhF = (const float*)d_in[2];
    const float* bF   = (const float*)d_in[3];
    const float* WihB = (const float*)d_in[4];
    const float* WhhB = (const float*)d_in[5];
    const float* bB   = (const float*)d_in[6];
    const float* dWih = (const float*)d_in[7];
    const float* dWhh = (const float*)d_in[8];
    const float* db   = (const float*)d_in[9];
    float* out = (float*)d_out;
    char* ws   = (char*)d_ws;

    void* args[] = { &seq, &WihF, &WhhF, &bF, &WihB, &WhhB, &bB,
                     &dWih, &dWhh, &db, &out, &ws };
    hipLaunchCooperativeKernel((void*)autoenc_kernel, dim3(128), dim3(512),
                               args, 0, stream);
}